// Round 5
// baseline (18.080 us; speedup 1.0000x reference)
//
#include <hip/hip_runtime.h>
#include <math.h>

#define NB 4
#define CC 128
#define HW 784        // 28*28
#define KK 64
#define DD 512
#define TD 8          // d-rows per block
#define BLK 832       // 13 waves; >= HW so each thread owns <=1 pixel

// Single fused kernel, one block per (n, 8-d-row group), 13 waves for TLP:
//   - thread t owns pixel p=t (t<784): streams x[n,:,p], accumulating the
//     8 conv dot-products AND the per-pixel sum-of-squares in one pass.
//     Weights are read with WAVE-UNIFORM indices straight from global so the
//     compiler scalarizes them into SGPRs (s_load, SALU pipe) — no LDS and no
//     per-lane VMEM on the weight path in the inner loop.
//   - feat = rinv*dot + bias staged in LDS
//   - waves 0..7 each do one row's softmax-weighted mean over P=784
//   - vlad[n,k,d] is k-independent (softmax over the spatial axis is invariant
//     to the per-(k,d) centroid shift) -> broadcast write via LDS
__global__ __launch_bounds__(BLK) void netvlad_fused_kernel(
    const float* __restrict__ x, const float* __restrict__ w,
    const float* __restrict__ b, float* __restrict__ out)
{
    __shared__ float feat_s[TD][HW];     // 25 KB
    __shared__ float g_s[TD];

    const int tid = threadIdx.x;
    const int n  = blockIdx.x >> 6;      // 64 d-groups per n
    const int d0 = (blockIdx.x & 63) * TD;
    const bool act = tid < HW;

    if (act) {
        const float* xp = x + (size_t)n * CC * HW + tid;
        const float* wb = w + (size_t)d0 * CC;    // 8 rows of 128, uniform base
        float acc[TD];
        #pragma unroll
        for (int j = 0; j < TD; ++j) acc[j] = 0.f;
        float sq = 0.f;

        // 8-deep unroll: 8 independent x loads in flight per chunk (ILP),
        // 64 uniform weight scalars hoisted as s_load per chunk (SALU).
        #pragma unroll 8
        for (int c = 0; c < CC; ++c) {
            float xv = xp[(size_t)c * HW];        // coalesced dword, L2-resident
            sq = fmaf(xv, xv, sq);
            #pragma unroll
            for (int j = 0; j < TD; ++j) {
                float wv = wb[j * CC + c];        // wave-uniform -> SGPR
                acc[j] = fmaf(wv, xv, acc[j]);
            }
        }

        float r = 1.0f / fmaxf(sqrtf(sq), 1e-12f);
        #pragma unroll
        for (int j = 0; j < TD; ++j)
            feat_s[j][tid] = fmaf(acc[j], r, b[d0 + j]);   // b uniform too
    }
    __syncthreads();

    // Per-row softmax-weighted mean over P=784; wave j (j<8) handles row j.
    const int lane = tid & 63;
    const int wave = tid >> 6;
    if (wave < TD) {
        const int j = wave;
        float m = -INFINITY;
        for (int p = lane; p < HW; p += 64) m = fmaxf(m, feat_s[j][p]);
        #pragma unroll
        for (int off = 32; off; off >>= 1) m = fmaxf(m, __shfl_xor(m, off, 64));
        float s = 0.f, ws = 0.f;
        for (int p = lane; p < HW; p += 64) {
            float f = feat_s[j][p];
            float e = __expf(f - m);
            s += e;
            ws = fmaf(e, f, ws);
        }
        #pragma unroll
        for (int off = 32; off; off >>= 1) {
            s  += __shfl_xor(s, off, 64);
            ws += __shfl_xor(ws, off, 64);
        }
        if (lane == 0) g_s[j] = ws / s;
    }
    __syncthreads();

    // Broadcast across k with a coalesced write: block owns out[n, :, d0:d0+8]
    if (tid < KK * TD) {
        int k = tid >> 3, j = tid & 7;
        out[(size_t)n * KK * DD + (size_t)k * DD + d0 + j] = g_s[j];
    }
}

extern "C" void kernel_launch(void* const* d_in, const int* in_sizes, int n_in,
                              void* d_out, int out_size, void* d_ws, size_t ws_size,
                              hipStream_t stream) {
    const float* x = (const float*)d_in[0];   // (4,128,28,28)
    const float* w = (const float*)d_in[1];   // (512,128)
    const float* b = (const float*)d_in[2];   // (512,)
    // d_in[3] = centroids (64,512): provably unused — softmax over the spatial
    // axis is invariant to the per-(k,d) constant shift, so vlad[n,k,d] is
    // identical for all k.
    float* out = (float*)d_out;               // (4,64,512) fp32

    netvlad_fused_kernel<<<NB * (DD / TD), BLK, 0, stream>>>(x, w, b, out);
}